// Round 2
// 356.669 us; speedup vs baseline: 1.0066x; 1.0066x over previous
//
#include <hip/hip_runtime.h>
#include <hip/hip_bf16.h>

// SimGCL / LightGCN 2-layer propagation — round 7b.
//   r6 -> r7:
//   - fused_scatter occupancy 12% -> ~95%: EPB 16384->8192, 1024-thread
//     blocks (489 blocks). gcur counters padded to 1/cacheline (GSTRIDE=16)
//     so the 143K reserve atomics don't serialize on 5 lines.
//   - agg: one destination per 8-lane SUB (8 dests/wave) instead of one
//     per wave: kills the 24-shfl cross-sub reduce, full-wave coalesced
//     stores, 8x fewer prologues. Full/tail loop split removes per-edge
//     bounds checks from the hot body. Non-temporal hints on streamed
//     edata/offsets/x/out to preserve L2 for the 19.2MB embb gather table.
//   r7 -> r7b: nontemporal builtins need native vector types, not
//     HIP_vector_type — use ext_vector_type(4) aliases for f32x4 paths.
//   Algebra (r4): y = dis*x (bf16); z[c] = dis[c]^2 * sum y[src];
//   out = (x + z/dis + dis * sum z[src]) / 3. No per-edge weights stored.

#define EMB_DIM 64
#define BUCKET_BITS 9
#define BUCKET_SZ 512
#define EPB 8192     // edges per partition block
#define NBMAX 512    // LDS capacity for bucket counters (NB = 293 actual)
#define CAP 16384    // per-bucket pairs capacity (mean 13651, sigma 117)
#define GSTRIDE 16   // 64B stride for gcur counters (atomic-line padding)

typedef float f32x4 __attribute__((ext_vector_type(4)));

__device__ __forceinline__ float bf_lo(unsigned int q) { return __uint_as_float(q << 16); }
__device__ __forceinline__ float bf_hi(unsigned int q) { return __uint_as_float(q & 0xffff0000u); }
__device__ __forceinline__ unsigned int f2bf(float f) {  // RNE
    unsigned int u = __float_as_uint(f);
    return (u + 0x7fffu + ((u >> 16) & 1u)) >> 16;
}

// (0) init per-bucket cursors to region starts
__global__ void init_kernel(int* __restrict__ gcur, int NB) {
    int t = threadIdx.x;
    if (t < NB) gcur[t * GSTRIDE] = t * CAP;
}

// (1) fused partition: LDS hist -> global reserve -> scatter, one kernel.
__global__ void fused_scatter(const int* __restrict__ rows,
                              const int* __restrict__ cols,
                              int* __restrict__ gcur,
                              unsigned int* __restrict__ pairs,
                              int E, int NB) {
    __shared__ int lh[NBMAX];
    __shared__ int lbase[NBMAX];
    __shared__ int lrank[NBMAX];
    int blk = blockIdx.x, t = threadIdx.x;
    for (int b = t; b < NB; b += blockDim.x) lh[b] = 0;
    __syncthreads();
    int start = blk * EPB, end = min(start + EPB, E);
    for (int i = start + t; i < end; i += blockDim.x)
        atomicAdd(&lh[cols[i] >> BUCKET_BITS], 1);
    __syncthreads();
    for (int b = t; b < NB; b += blockDim.x) {
        int c = lh[b];
        lbase[b] = c ? atomicAdd(&gcur[b * GSTRIDE], c) : 0;
        lrank[b] = 0;
    }
    __syncthreads();
    for (int i = start + t; i < end; i += blockDim.x) {
        int c = cols[i];              // L2-hot re-read
        int r = rows[i];
        int b = c >> BUCKET_BITS;
        int rk = atomicAdd(&lrank[b], 1);
        pairs[lbase[b] + rk] = (unsigned)r | ((unsigned)(c & (BUCKET_SZ - 1)) << 18);
    }
}

// (2) scan bucket counts (NB <= 512) -> gbase (exclusive, for edata);
//     also offsets[N] = E.
__global__ void count_scan(const int* __restrict__ gcur,
                           int* __restrict__ gbase,
                           int* __restrict__ offsets, int NB, int N, int E) {
    __shared__ int lds[NBMAX];
    int t = threadIdx.x;
    int v = (t < NB) ? (gcur[t * GSTRIDE] - t * CAP) : 0;
    lds[t] = v;
    __syncthreads();
    for (int off = 1; off < NBMAX; off <<= 1) {
        int u = (t >= off) ? lds[t - off] : 0;
        __syncthreads();
        lds[t] += u;
        __syncthreads();
    }
    if (t < NB) gbase[t] = lds[t] - v;
    if (t == 0) offsets[N] = E;
}

// (3) per-bucket finalize: counting sort by col; emits dis[], offsets[],
//     col-sorted src -> edata; fused y = dis*x -> bf16 for bucket's rows.
__global__ void bucket_finalize(const unsigned int* __restrict__ pairs,
                                const int* __restrict__ gcur,
                                const int* __restrict__ gbase,
                                const float* __restrict__ x,
                                int* __restrict__ edata,
                                int* __restrict__ offsets,
                                float* __restrict__ dis,
                                unsigned short* __restrict__ yb,
                                int N, int E, int NB) {
    __shared__ int ccnt[BUCKET_SZ];
    __shared__ int cexc[BUCKET_SZ];
    __shared__ int sc[1024];
    int b = blockIdx.x, t = threadIdx.x;
    int pbase = b * CAP;
    int cnt = gcur[b * GSTRIDE] - pbase;
    int base = gbase[b];
    int col0 = b << BUCKET_BITS;
    int ncols = min(BUCKET_SZ, N - col0);

    if (t < BUCKET_SZ) ccnt[t] = 0;
    __syncthreads();
    for (int i = t; i < cnt; i += blockDim.x)
        atomicAdd(&ccnt[pairs[pbase + i] >> 18], 1);
    __syncthreads();

    int v = (t < BUCKET_SZ) ? ccnt[t] : 0;
    sc[t] = v;
    __syncthreads();
    for (int off = 1; off < 1024; off <<= 1) {
        int u = (t >= off) ? sc[t - off] : 0;
        __syncthreads();
        sc[t] += u;
        __syncthreads();
    }
    if (t < BUCKET_SZ) cexc[t] = sc[t] - v;
    __syncthreads();

    if (t < ncols) {
        int c = ccnt[t];
        offsets[col0 + t] = base + cexc[t];
        dis[col0 + t] = (c > 0) ? rsqrtf((float)c) : 0.0f;
    }
    // reuse sc[0..511] as rank counters
    if (t < BUCKET_SZ) sc[t] = 0;
    __syncthreads();
    for (int i = t; i < cnt; i += blockDim.x) {
        unsigned p = pairs[pbase + i];
        int lc = p >> 18;
        int src = p & 0x3FFFF;
        int rk = atomicAdd(&sc[lc], 1);
        edata[base + cexc[lc] + rk] = src;
    }

    // fused: y[row] = dis[row] * x[row] in bf16 (ccnt stable).
    for (int u = t; u < ncols * 16; u += blockDim.x) {
        int lr = u >> 4;
        int part = u & 15;
        int c = ccnt[lr];
        float d = (c > 0) ? rsqrtf((float)c) : 0.0f;
        size_t o = (((size_t)(col0 + lr)) << 6) + part * 4;
        float4 vx = *(const float4*)(x + o);
        uint2 w;
        w.x = f2bf(vx.x * d) | (f2bf(vx.y * d) << 16);
        w.y = f2bf(vx.z * d) | (f2bf(vx.w * d) << 16);
        *(uint2*)(yb + o) = w;
    }
}

__device__ __forceinline__ void acc8(float* acc, uint4 q) {
    acc[0] += bf_lo(q.x);
    acc[1] += bf_hi(q.x);
    acc[2] += bf_lo(q.y);
    acc[3] += bf_hi(q.y);
    acc[4] += bf_lo(q.z);
    acc[5] += bf_hi(q.z);
    acc[6] += bf_lo(q.w);
    acc[7] += bf_hi(q.w);
}

// Wave = 8 subgroups x 8 lanes; each SUB owns ONE destination node
// (8 dests per wave, no cross-sub reduce). Lane holds 8 fp32 dims.
// Hot loop = 4 edges in flight per sub, no bounds checks (full/tail split).
// !FINAL (embb = yb):  zb[c] = bf16( dis[c]^2 * acc )
//  FINAL (embb = zb):  out = (x + zb/dis + dis*acc)/3
template <bool FINAL>
__global__ void agg_kernel(const unsigned short* __restrict__ embb,
                           const int* __restrict__ edata,
                           const int* __restrict__ offsets,
                           const float* __restrict__ dis,
                           const float* __restrict__ x,        // FINAL only
                           unsigned short* __restrict__ outb,  // !FINAL
                           float* __restrict__ outf,           // FINAL
                           int n) {
    int wave = (blockIdx.x * blockDim.x + threadIdx.x) >> 6;
    int lane = threadIdx.x & 63;
    int sub = lane >> 3;
    int dest = (wave << 3) + sub;
    if (dest >= n) return;
    int dimo = (lane & 7) * 8;

    int s = __builtin_nontemporal_load(offsets + dest);
    int e = __builtin_nontemporal_load(offsets + dest + 1);

    float acc[8] = {0, 0, 0, 0, 0, 0, 0, 0};

    int k = s;
    int kfull = s + ((e - s) & ~3);
    for (; k < kfull; k += 4) {
        int s0 = __builtin_nontemporal_load(edata + k);
        int s1 = __builtin_nontemporal_load(edata + k + 1);
        int s2 = __builtin_nontemporal_load(edata + k + 2);
        int s3 = __builtin_nontemporal_load(edata + k + 3);
        uint4 q0 = *(const uint4*)(embb + ((size_t)s0 << 6) + dimo);
        uint4 q1 = *(const uint4*)(embb + ((size_t)s1 << 6) + dimo);
        uint4 q2 = *(const uint4*)(embb + ((size_t)s2 << 6) + dimo);
        uint4 q3 = *(const uint4*)(embb + ((size_t)s3 << 6) + dimo);
        acc8(acc, q0);
        acc8(acc, q1);
        acc8(acc, q2);
        acc8(acc, q3);
    }
    for (; k < e; ++k) {
        int s0 = __builtin_nontemporal_load(edata + k);
        uint4 q0 = *(const uint4*)(embb + ((size_t)s0 << 6) + dimo);
        acc8(acc, q0);
    }

    float dc = dis[dest];
    size_t o = ((size_t)dest << 6) + dimo;
    if (FINAL) {
        float rd = (dc > 0.0f) ? 1.0f / dc : 0.0f;  // emb1 = z * rd
        f32x4 xa = __builtin_nontemporal_load((const f32x4*)(x + o));
        f32x4 xc = __builtin_nontemporal_load((const f32x4*)(x + o) + 1);
        uint4 qz = *(const uint4*)(embb + o);  // own z (bf16), L2-hot
        const float k3 = 1.0f / 3.0f;
        f32x4 r0, r1;
        r0.x = (xa.x + bf_lo(qz.x) * rd + dc * acc[0]) * k3;
        r0.y = (xa.y + bf_hi(qz.x) * rd + dc * acc[1]) * k3;
        r0.z = (xa.z + bf_lo(qz.y) * rd + dc * acc[2]) * k3;
        r0.w = (xa.w + bf_hi(qz.y) * rd + dc * acc[3]) * k3;
        r1.x = (xc.x + bf_lo(qz.z) * rd + dc * acc[4]) * k3;
        r1.y = (xc.y + bf_hi(qz.z) * rd + dc * acc[5]) * k3;
        r1.z = (xc.z + bf_lo(qz.w) * rd + dc * acc[6]) * k3;
        r1.w = (xc.w + bf_hi(qz.w) * rd + dc * acc[7]) * k3;
        __builtin_nontemporal_store(r0, (f32x4*)(outf + o));
        __builtin_nontemporal_store(r1, (f32x4*)(outf + o) + 1);
    } else {
        float zs = dc * dc;  // z = dis^2 * acc
        uint4 q;
        q.x = f2bf(zs * acc[0]) | (f2bf(zs * acc[1]) << 16);
        q.y = f2bf(zs * acc[2]) | (f2bf(zs * acc[3]) << 16);
        q.z = f2bf(zs * acc[4]) | (f2bf(zs * acc[5]) << 16);
        q.w = f2bf(zs * acc[6]) | (f2bf(zs * acc[7]) << 16);
        *(uint4*)(outb + o) = q;  // reused next layer: keep cached
    }
}

extern "C" void kernel_launch(void* const* d_in, const int* in_sizes, int n_in,
                              void* d_out, int out_size, void* d_ws, size_t ws_size,
                              hipStream_t stream) {
    const float* x  = (const float*)d_in[0];
    const int*   ei = (const int*)d_in[1];
    const int E = in_sizes[1] / 2;
    const int N = in_sizes[0] / EMB_DIM;  // 150000

    const int* rows = ei;       // edge_index[0]
    const int* cols = ei + E;   // edge_index[1]

    const int NB = (N + BUCKET_SZ - 1) >> BUCKET_BITS;  // 293
    const int NBLK = (E + EPB - 1) / EPB;               // 489

    // Workspace layout (ints):
    //   gcur[512*GSTRIDE] gbase[512]
    //   dis[150080] offsets[150080] edata[E]
    //   yb[N*64 bf16] = 4.8M ints
    //   region R: zb[N*64 bf16] overlapped by pairs[NB*CAP] (dead before agg1)
    int*   gcur    = (int*)d_ws;
    int*   gbase   = gcur + 512 * GSTRIDE;
    float* dis     = (float*)(gbase + 512);
    int*   offsets = (int*)(dis + 150080);
    int*   edata   = offsets + 150080;
    unsigned short* yb = (unsigned short*)(edata + E);
    unsigned short* zb = yb + (size_t)N * EMB_DIM;
    unsigned int* pairs = (unsigned int*)zb;  // lifetime: fused_scatter..finalize
    float* out = (float*)d_out;

    init_kernel<<<1, 512, 0, stream>>>(gcur, NB);
    fused_scatter<<<NBLK, 1024, 0, stream>>>(rows, cols, gcur, pairs, E, NB);
    count_scan<<<1, 512, 0, stream>>>(gcur, gbase, offsets, NB, N, E);
    bucket_finalize<<<NB, 1024, 0, stream>>>(pairs, gcur, gbase, x, edata,
                                             offsets, dis, yb, N, E, NB);

    int agg_waves = (N + 7) / 8;                 // 8 dests per wave
    int agg_blocks = (agg_waves + 3) / 4;        // 4 waves per 256-thread block
    // layer 1: yb -> zb (= dis^2 * sum y)
    agg_kernel<false><<<agg_blocks, 256, 0, stream>>>(yb, edata, offsets, dis,
                                                      nullptr, zb, nullptr, N);
    // layer 2 + final: out = (x + zb/dis + dis*sum zb[src]) / 3
    agg_kernel<true><<<agg_blocks, 256, 0, stream>>>(zb, edata, offsets, dis,
                                                     x, nullptr, out, N);
}